// Round 1
// baseline (32095.389 us; speedup 1.0000x reference)
//
#include <hip/hip_runtime.h>
#include <hip/hip_fp16.h>
#include <hip/hip_cooperative_groups.h>

namespace cg = cooperative_groups;

typedef _Float16 half8 __attribute__((ext_vector_type(8)));
typedef float floatx4 __attribute__((ext_vector_type(4)));

#define NB 128
#define NT 256
#define NIN 128
#define NH 1024

// ws layout (bytes)
#define H0_OFF   0u          // 2 * 128*1024 half = 524288 B
#define H1_OFF   524288u     // 524288 B
#define X16_OFF  1048576u    // 128*256*128 half = 8388608 B
#define W0_OFF   9437184u    // 4096*1152 half = 9437184 B
#define W1_OFF   18874368u   // 4096*2048 half = 16777216 B -> end 35651584

__device__ __forceinline__ float sigm(float x) { return 1.0f / (1.0f + __expf(-x)); }
__device__ __forceinline__ float tanh_fast(float x) { return 1.0f - 2.0f / (__expf(2.0f * x) + 1.0f); }

__global__ void __launch_bounds__(512)
lstm_persist(const float* __restrict__ x,
             const float* __restrict__ Wih0, const float* __restrict__ Whh0,
             const float* __restrict__ bih0, const float* __restrict__ bhh0,
             const float* __restrict__ Wih1, const float* __restrict__ Whh1,
             const float* __restrict__ bih1, const float* __restrict__ bhh1,
             const float* __restrict__ Wd, const float* __restrict__ bd,
             float* __restrict__ out, char* __restrict__ wsc)
{
    cg::grid_group grid = cg::this_grid();
    const int wg   = blockIdx.x;      // 0..255, owns h-cols [wg*4, wg*4+4)
    const int tid  = threadIdx.x;     // 0..511
    const int wave = tid >> 6;        // 0..7, owns batch rows [wave*16, wave*16+16)
    const int lane = tid & 63;
    const int l15  = lane & 15;
    const int quad = lane >> 4;

    _Float16* h0b = (_Float16*)(wsc + H0_OFF);   // [2][128][1024]
    _Float16* h1b = (_Float16*)(wsc + H1_OFF);   // [2][128][1024]
    _Float16* x16 = (_Float16*)(wsc + X16_OFF);  // [128][256][128]
    _Float16* w0l = (_Float16*)(wsc + W0_OFF);   // [256 wg][16 c][1152 k]
    _Float16* w1l = (_Float16*)(wsc + W1_OFF);   // [256 wg][16 c][2048 k]

    __shared__ float gs0[128][17];
    __shared__ float gs1[128][17];
    __shared__ float bs0[16], bs1[16];

    // ---------- init phase: zero h bufs, convert x & weights to fp16 ----------
    {
        const int gtid = wg * 512 + tid;
        const int gsz  = 256 * 512;  // 131072
        float* hz = (float*)wsc;     // both h bufs = 1 MiB = 262144 floats
        for (int i = gtid; i < 262144; i += gsz) hz[i] = 0.0f;
        for (int i = gtid; i < NB * NT * NIN; i += gsz) x16[i] = (_Float16)x[i];
        // layer0 weights: [wg][c][k], k<128 from W_ih0 row gcol, else W_hh0
        for (int i = gtid; i < 4096 * 1152; i += gsz) {
            int row = i / 1152; int k = i - row * 1152;
            int w_ = row >> 4, c = row & 15;
            int gcol = ((c >> 2) << 10) + (w_ << 2) + (c & 3);
            float v = (k < NIN) ? Wih0[gcol * NIN + k] : Whh0[gcol * NH + (k - NIN)];
            w0l[i] = (_Float16)v;
        }
        // layer1 weights: [wg][c][k], k<1024 from W_ih1 (input h0), else W_hh1 (h1)
        for (int i = gtid; i < 4096 * 2048; i += gsz) {
            int row = i >> 11, k = i & 2047;
            int w_ = row >> 4, c = row & 15;
            int gcol = ((c >> 2) << 10) + (w_ << 2) + (c & 3);
            float v = (k < NH) ? Wih1[gcol * NH + k] : Whh1[gcol * NH + (k - NH)];
            w1l[i] = (_Float16)v;
        }
        if (tid < 16) {
            int c = tid;
            int gcol = ((c >> 2) << 10) + (wg << 2) + (c & 3);
            bs0[c] = bih0[gcol] + bhh0[gcol];
            bs1[c] = bih1[gcol] + bhh1[gcol];
        }
    }
    __threadfence();
    grid.sync();

    float c0 = 0.0f, c1 = 0.0f;          // persistent cell state, 1 (b,hcol) pair/thread
    const int b_act = tid >> 2;          // batch row for activation stage
    const int jl    = tid & 3;           // local h-col
    const int hcol  = (wg << 2) + jl;

    // B-fragment row bases (n = l15), A k-offset quad*8 baked in
    const _Float16* w0row = w0l + (size_t)(wg * 16 + l15) * 1152 + quad * 8;
    const _Float16* w1row = w1l + (size_t)(wg * 16 + l15) * 2048 + quad * 8;

    // pipeline: phase p computes h0[p] (p<NT) and h1[p-1] (p>=1)
    for (int p = 0; p <= NT; ++p) {
        const _Float16* h0prev = h0b + ((p - 1) & 1) * (NB * NH);  // h0[p-1]
        const _Float16* h1pp   = h1b + (p & 1) * (NB * NH);        // h1[p-2]

        floatx4 acc0 = {0.f, 0.f, 0.f, 0.f};
        floatx4 acc1 = {0.f, 0.f, 0.f, 0.f};

        const _Float16* arow_h0 = h0prev + (size_t)(wave * 16 + l15) * NH + quad * 8;

        if (p < NT) {
            // x_t contribution to layer0 gates (K = 0..127)
            const _Float16* arow_x = x16 + (size_t)(wave * 16 + l15) * (NT * NIN) + p * NIN + quad * 8;
            #pragma unroll
            for (int kc = 0; kc < 4; ++kc) {
                half8 a = *(const half8*)(arow_x + kc * 32);
                half8 b = *(const half8*)(w0row + kc * 32);
                acc0 = __builtin_amdgcn_mfma_f32_16x16x32_f16(a, b, acc0, 0, 0, 0);
            }
        }

        // h0[p-1] contribution: feeds BOTH layer0 (W_hh0) and layer1 (W_ih1) — share A loads
        if (p >= 1 && p < NT) {
            const _Float16* b0 = w0row + NIN;
            #pragma unroll 8
            for (int kc = 0; kc < 32; ++kc) {
                half8 a  = *(const half8*)(arow_h0 + kc * 32);
                half8 v0 = *(const half8*)(b0 + kc * 32);
                half8 v1 = *(const half8*)(w1row + kc * 32);
                acc0 = __builtin_amdgcn_mfma_f32_16x16x32_f16(a, v0, acc0, 0, 0, 0);
                acc1 = __builtin_amdgcn_mfma_f32_16x16x32_f16(a, v1, acc1, 0, 0, 0);
            }
        } else if (p < NT) {  // p == 0
            const _Float16* b0 = w0row + NIN;
            #pragma unroll 8
            for (int kc = 0; kc < 32; ++kc) {
                half8 a  = *(const half8*)(arow_h0 + kc * 32);
                half8 v0 = *(const half8*)(b0 + kc * 32);
                acc0 = __builtin_amdgcn_mfma_f32_16x16x32_f16(a, v0, acc0, 0, 0, 0);
            }
        } else {              // p == NT
            #pragma unroll 8
            for (int kc = 0; kc < 32; ++kc) {
                half8 a  = *(const half8*)(arow_h0 + kc * 32);
                half8 v1 = *(const half8*)(w1row + kc * 32);
                acc1 = __builtin_amdgcn_mfma_f32_16x16x32_f16(a, v1, acc1, 0, 0, 0);
            }
        }

        if (p >= 1) {
            // h1[p-2] contribution to layer1 gates (K = 1024..2047)
            const _Float16* arow_h1 = h1pp + (size_t)(wave * 16 + l15) * NH + quad * 8;
            const _Float16* b1 = w1row + NH;
            #pragma unroll 8
            for (int kc = 0; kc < 32; ++kc) {
                half8 a = *(const half8*)(arow_h1 + kc * 32);
                half8 v = *(const half8*)(b1 + kc * 32);
                acc1 = __builtin_amdgcn_mfma_f32_16x16x32_f16(a, v, acc1, 0, 0, 0);
            }
        }

        // stash gate tiles to LDS (C/D layout: col=lane&15, row=quad*4+r)
        if (p < NT) {
            #pragma unroll
            for (int r = 0; r < 4; ++r) gs0[wave * 16 + quad * 4 + r][l15] = acc0[r];
        }
        if (p >= 1) {
            #pragma unroll
            for (int r = 0; r < 4; ++r) gs1[wave * 16 + quad * 4 + r][l15] = acc1[r];
        }
        __syncthreads();

        // activation: 1 (b, hcol) pair per thread; gate cols c = gate*4 + jl
        if (p < NT) {
            float gi = gs0[b_act][jl]      + bs0[jl];
            float gf = gs0[b_act][4 + jl]  + bs0[4 + jl];
            float gg = gs0[b_act][8 + jl]  + bs0[8 + jl];
            float go = gs0[b_act][12 + jl] + bs0[12 + jl];
            c0 = sigm(gf) * c0 + sigm(gi) * tanh_fast(gg);
            float h = sigm(go) * tanh_fast(c0);
            h0b[(p & 1) * (NB * NH) + b_act * NH + hcol] = (_Float16)h;
        }
        if (p >= 1) {
            float gi = gs1[b_act][jl]      + bs1[jl];
            float gf = gs1[b_act][4 + jl]  + bs1[4 + jl];
            float gg = gs1[b_act][8 + jl]  + bs1[8 + jl];
            float go = gs1[b_act][12 + jl] + bs1[12 + jl];
            c1 = sigm(gf) * c1 + sigm(gi) * tanh_fast(gg);
            float h = sigm(go) * tanh_fast(c1);
            h1b[((p - 1) & 1) * (NB * NH) + b_act * NH + hcol] = (_Float16)h;
        }
        __threadfence();
        grid.sync();
    }

    // dense head: out[b][o] = tanh(h1[T-1] . Wd[o] + bd[o]); h1[255] at parity 1
    if (wg == 0 && tid < NB * 2) {
        int b = tid >> 1, o = tid & 1;
        const _Float16* hrow = h1b + (NB * NH) + b * NH;
        float s = bd[o];
        for (int k = 0; k < NH; ++k) s += (float)hrow[k] * Wd[o * NH + k];
        out[b * 2 + o] = tanhf(s);
    }
}

extern "C" void kernel_launch(void* const* d_in, const int* in_sizes, int n_in,
                              void* d_out, int out_size, void* d_ws, size_t ws_size,
                              hipStream_t stream) {
    const float* x    = (const float*)d_in[0];
    const float* Wih0 = (const float*)d_in[1];
    const float* Whh0 = (const float*)d_in[2];
    const float* bih0 = (const float*)d_in[3];
    const float* bhh0 = (const float*)d_in[4];
    const float* Wih1 = (const float*)d_in[5];
    const float* Whh1 = (const float*)d_in[6];
    const float* bih1 = (const float*)d_in[7];
    const float* bhh1 = (const float*)d_in[8];
    const float* Wd   = (const float*)d_in[9];
    const float* bd   = (const float*)d_in[10];
    float* out = (float*)d_out;
    char* ws = (char*)d_ws;

    void* kargs[] = { &x, &Wih0, &Whh0, &bih0, &bhh0, &Wih1, &Whh1, &bih1, &bhh1,
                      &Wd, &bd, &out, &ws };
    hipLaunchCooperativeKernel((void*)lstm_persist, dim3(256), dim3(512),
                               kargs, 0, stream);
}

// Round 2
// 27083.655 us; speedup vs baseline: 1.1850x; 1.1850x over previous
//
#include <hip/hip_runtime.h>
#include <hip/hip_fp16.h>
#include <hip/hip_cooperative_groups.h>

namespace cg = cooperative_groups;

typedef _Float16 half8 __attribute__((ext_vector_type(8)));
typedef float floatx4 __attribute__((ext_vector_type(4)));

#define NB 128
#define NT 256
#define NIN 128
#define NH 1024

// ws layout (bytes): h ping-pong buffers + fp16 x copy only (weights live in LDS)
#define H0_OFF   0u          // 2 * 128*1024 half = 524288 B
#define H1_OFF   524288u     // 524288 B
#define X16_OFF  1048576u    // 128*256*128 half = 8388608 B -> end 9437184

// LDS layout (bytes), carved from extern __shared__:
//  w0l: 16 cols x (1152+8) half = 37120
//  w1l: 16 cols x (2048+8) half = 65792   (base 37120)
//  gs0: 16 cols x 132 float     =  8448   (base 102912) col-major gate tile
//  gs1: 16 cols x 132 float     =  8448   (base 111360)
//  bs0/bs1: 16+16 float         =   128   (base 119808) -> total 119936
#define W0STRIDE 1160
#define W1STRIDE 2056
#define GSTRIDE  132
#define LDS_BYTES 119936

__device__ __forceinline__ float sigm(float x) { return 1.0f / (1.0f + __expf(-x)); }
__device__ __forceinline__ float tanh_fast(float x) { return 1.0f - 2.0f / (__expf(2.0f * x) + 1.0f); }

__global__ void __launch_bounds__(512)
lstm_persist(const float* __restrict__ x,
             const float* __restrict__ Wih0, const float* __restrict__ Whh0,
             const float* __restrict__ bih0, const float* __restrict__ bhh0,
             const float* __restrict__ Wih1, const float* __restrict__ Whh1,
             const float* __restrict__ bih1, const float* __restrict__ bhh1,
             const float* __restrict__ Wd, const float* __restrict__ bd,
             float* __restrict__ out, char* __restrict__ wsc)
{
    cg::grid_group grid = cg::this_grid();
    const int wg   = blockIdx.x;      // 0..255, owns h-cols [wg*4, wg*4+4)
    const int tid  = threadIdx.x;     // 0..511
    const int wave = tid >> 6;        // 0..7, owns batch rows [wave*16, wave*16+16)
    const int lane = tid & 63;
    const int l15  = lane & 15;
    const int quad = lane >> 4;

    _Float16* h0b = (_Float16*)(wsc + H0_OFF);   // [2][128][1024]
    _Float16* h1b = (_Float16*)(wsc + H1_OFF);   // [2][128][1024]
    _Float16* x16 = (_Float16*)(wsc + X16_OFF);  // [128][256][128]

    extern __shared__ char smem[];
    _Float16* w0l = (_Float16*)(smem);            // [16][1160]
    _Float16* w1l = (_Float16*)(smem + 37120);    // [16][2056]
    float*    gs0 = (float*)(smem + 102912);      // [16][132] col-major
    float*    gs1 = (float*)(smem + 111360);      // [16][132]
    float*    bs0 = (float*)(smem + 119808);      // [16]
    float*    bs1 = (float*)(smem + 119808 + 64); // [16]

    // ---------- init: stage this WG's weight slice into LDS (fp16) ----------
    for (int i = tid; i < 16 * 1152; i += 512) {
        int c = i / 1152, k = i - c * 1152;
        int gcol = ((c >> 2) << 10) + (wg << 2) + (c & 3);
        float v = (k < NIN) ? Wih0[gcol * NIN + k] : Whh0[gcol * NH + (k - NIN)];
        w0l[c * W0STRIDE + k] = (_Float16)v;
    }
    for (int i = tid; i < 16 * 2048; i += 512) {
        int c = i >> 11, k = i & 2047;
        int gcol = ((c >> 2) << 10) + (wg << 2) + (c & 3);
        float v = (k < NH) ? Wih1[gcol * NH + k] : Whh1[gcol * NH + (k - NH)];
        w1l[c * W1STRIDE + k] = (_Float16)v;
    }
    if (tid < 16) {
        int c = tid;
        int gcol = ((c >> 2) << 10) + (wg << 2) + (c & 3);
        bs0[c] = bih0[gcol] + bhh0[gcol];
        bs1[c] = bih1[gcol] + bhh1[gcol];
    }

    // ---------- init: zero h bufs, convert x to fp16 (grid-strided) ----------
    {
        const int gtid = wg * 512 + tid;
        const int gsz  = 256 * 512;  // 131072
        float* hz = (float*)wsc;     // both h bufs = 1 MiB = 262144 floats
        for (int i = gtid; i < 262144; i += gsz) hz[i] = 0.0f;
        for (int i = gtid; i < NB * NT * NIN; i += gsz) x16[i] = (_Float16)x[i];
    }
    __builtin_amdgcn_fence(__ATOMIC_RELEASE, "agent");
    grid.sync();
    __builtin_amdgcn_fence(__ATOMIC_ACQUIRE, "agent");

    float c0 = 0.0f, c1 = 0.0f;          // persistent cell state, 1 (b,hcol) pair/thread
    const int b_act = tid >> 2;          // batch row for activation stage
    const int jl    = tid & 3;           // local h-col
    const int hcol  = (wg << 2) + jl;

    // B-fragment row bases in LDS (n = l15), A k-offset quad*8 baked in
    const _Float16* w0row = w0l + l15 * W0STRIDE + quad * 8;
    const _Float16* w1row = w1l + l15 * W1STRIDE + quad * 8;

    // pipeline: phase p computes h0[p] (p<NT) and h1[p-1] (p>=1)
    for (int p = 0; p <= NT; ++p) {
        const _Float16* h0prev = h0b + ((p - 1) & 1) * (NB * NH);  // h0[p-1]
        const _Float16* h1pp   = h1b + (p & 1) * (NB * NH);        // h1[p-2]

        floatx4 acc0 = {0.f, 0.f, 0.f, 0.f};
        floatx4 acc1 = {0.f, 0.f, 0.f, 0.f};

        const _Float16* arow_h0 = h0prev + (size_t)(wave * 16 + l15) * NH + quad * 8;

        if (p < NT) {
            // x_t contribution to layer0 gates (K = 0..127)
            const _Float16* arow_x = x16 + (size_t)(wave * 16 + l15) * (NT * NIN) + p * NIN + quad * 8;
            #pragma unroll
            for (int kc = 0; kc < 4; ++kc) {
                half8 a = *(const half8*)(arow_x + kc * 32);
                half8 b = *(const half8*)(w0row + kc * 32);
                acc0 = __builtin_amdgcn_mfma_f32_16x16x32_f16(a, b, acc0, 0, 0, 0);
            }
        }

        // h0[p-1] contribution: feeds BOTH layer0 (W_hh0) and layer1 (W_ih1) — share A loads
        if (p >= 1 && p < NT) {
            const _Float16* b0 = w0row + NIN;
            #pragma unroll 8
            for (int kc = 0; kc < 32; ++kc) {
                half8 a  = *(const half8*)(arow_h0 + kc * 32);
                half8 v0 = *(const half8*)(b0 + kc * 32);
                half8 v1 = *(const half8*)(w1row + kc * 32);
                acc0 = __builtin_amdgcn_mfma_f32_16x16x32_f16(a, v0, acc0, 0, 0, 0);
                acc1 = __builtin_amdgcn_mfma_f32_16x16x32_f16(a, v1, acc1, 0, 0, 0);
            }
        } else if (p < NT) {  // p == 0
            const _Float16* b0 = w0row + NIN;
            #pragma unroll 8
            for (int kc = 0; kc < 32; ++kc) {
                half8 a  = *(const half8*)(arow_h0 + kc * 32);
                half8 v0 = *(const half8*)(b0 + kc * 32);
                acc0 = __builtin_amdgcn_mfma_f32_16x16x32_f16(a, v0, acc0, 0, 0, 0);
            }
        } else {              // p == NT
            #pragma unroll 8
            for (int kc = 0; kc < 32; ++kc) {
                half8 a  = *(const half8*)(arow_h0 + kc * 32);
                half8 v1 = *(const half8*)(w1row + kc * 32);
                acc1 = __builtin_amdgcn_mfma_f32_16x16x32_f16(a, v1, acc1, 0, 0, 0);
            }
        }

        if (p >= 1) {
            // h1[p-2] contribution to layer1 gates (K = 1024..2047)
            const _Float16* arow_h1 = h1pp + (size_t)(wave * 16 + l15) * NH + quad * 8;
            const _Float16* b1 = w1row + NH;
            #pragma unroll 8
            for (int kc = 0; kc < 32; ++kc) {
                half8 a = *(const half8*)(arow_h1 + kc * 32);
                half8 v = *(const half8*)(b1 + kc * 32);
                acc1 = __builtin_amdgcn_mfma_f32_16x16x32_f16(a, v, acc1, 0, 0, 0);
            }
        }

        // stash gate tiles to LDS, col-major: rows quad*4+r contiguous -> one b128
        if (p < NT) *(floatx4*)&gs0[l15 * GSTRIDE + wave * 16 + quad * 4] = acc0;
        if (p >= 1) *(floatx4*)&gs1[l15 * GSTRIDE + wave * 16 + quad * 4] = acc1;
        __syncthreads();

        // activation: 1 (b, hcol) pair per thread; gate cols c = gate*4 + jl
        if (p < NT) {
            float gi = gs0[(jl)      * GSTRIDE + b_act] + bs0[jl];
            float gf = gs0[(4 + jl)  * GSTRIDE + b_act] + bs0[4 + jl];
            float gg = gs0[(8 + jl)  * GSTRIDE + b_act] + bs0[8 + jl];
            float go = gs0[(12 + jl) * GSTRIDE + b_act] + bs0[12 + jl];
            c0 = sigm(gf) * c0 + sigm(gi) * tanh_fast(gg);
            float h = sigm(go) * tanh_fast(c0);
            h0b[(p & 1) * (NB * NH) + b_act * NH + hcol] = (_Float16)h;
        }
        if (p >= 1) {
            float gi = gs1[(jl)      * GSTRIDE + b_act] + bs1[jl];
            float gf = gs1[(4 + jl)  * GSTRIDE + b_act] + bs1[4 + jl];
            float gg = gs1[(8 + jl)  * GSTRIDE + b_act] + bs1[8 + jl];
            float go = gs1[(12 + jl) * GSTRIDE + b_act] + bs1[12 + jl];
            c1 = sigm(gf) * c1 + sigm(gi) * tanh_fast(gg);
            float h = sigm(go) * tanh_fast(c1);
            h1b[((p - 1) & 1) * (NB * NH) + b_act * NH + hcol] = (_Float16)h;
        }
        __builtin_amdgcn_fence(__ATOMIC_RELEASE, "agent");
        grid.sync();
        __builtin_amdgcn_fence(__ATOMIC_ACQUIRE, "agent");
    }

    // dense head: out[b][o] = tanh(h1[T-1] . Wd[o] + bd[o]); h1[255] at parity 1
    if (wg == 0 && tid < NB * 2) {
        int b = tid >> 1, o = tid & 1;
        const _Float16* hrow = h1b + (NB * NH) + b * NH;
        float s = bd[o];
        for (int k = 0; k < NH; ++k) s += (float)hrow[k] * Wd[o * NH + k];
        out[b * 2 + o] = tanhf(s);
    }
}

extern "C" void kernel_launch(void* const* d_in, const int* in_sizes, int n_in,
                              void* d_out, int out_size, void* d_ws, size_t ws_size,
                              hipStream_t stream) {
    const float* x    = (const float*)d_in[0];
    const float* Wih0 = (const float*)d_in[1];
    const float* Whh0 = (const float*)d_in[2];
    const float* bih0 = (const float*)d_in[3];
    const float* bhh0 = (const float*)d_in[4];
    const float* Wih1 = (const float*)d_in[5];
    const float* Whh1 = (const float*)d_in[6];
    const float* bih1 = (const float*)d_in[7];
    const float* bhh1 = (const float*)d_in[8];
    const float* Wd   = (const float*)d_in[9];
    const float* bd   = (const float*)d_in[10];
    float* out = (float*)d_out;
    char* ws = (char*)d_ws;

    // dynamic LDS > 64 KB needs the attribute raised; idempotent, safe per-call
    hipFuncSetAttribute((const void*)lstm_persist,
                        hipFuncAttributeMaxDynamicSharedMemorySize, LDS_BYTES);

    void* kargs[] = { &x, &Wih0, &Whh0, &bih0, &bhh0, &Wih1, &Whh1, &bih1, &bhh1,
                      &Wd, &bd, &out, &ws };
    hipLaunchCooperativeKernel((void*)lstm_persist, dim3(256), dim3(512),
                               kargs, LDS_BYTES, stream);
}

// Round 3
// 8375.297 us; speedup vs baseline: 3.8321x; 3.2338x over previous
//
#include <hip/hip_runtime.h>
#include <hip/hip_fp16.h>
#include <hip/hip_cooperative_groups.h>

namespace cg = cooperative_groups;

typedef _Float16 half8 __attribute__((ext_vector_type(8)));
typedef float floatx4 __attribute__((ext_vector_type(4)));

#define NB 128
#define NT 256
#define NIN 128
#define NH 1024

// ws layout (bytes): h ping-pong buffers + fp16 x copy + barrier state
#define H0_OFF   0u          // 2 * 128*1024 half = 524288 B
#define H1_OFF   524288u     // 524288 B
#define X16_OFF  1048576u    // 128*256*128 half = 8388608 B
#define BAR_OFF  9437184u    // 2 x unsigned (padded) -> end 9437312

// LDS layout (bytes), carved from extern __shared__:
//  w0l: 16 cols x (1152+8) half = 37120
//  w1l: 16 cols x (2048+8) half = 65792   (base 37120)
//  gs0: 16 cols x 132 float     =  8448   (base 102912) col-major gate tile
//  gs1: 16 cols x 132 float     =  8448   (base 111360)
//  bs0/bs1: 16+16 float         =   128   (base 119808) -> total 119936
#define W0STRIDE 1160
#define W1STRIDE 2056
#define GSTRIDE  132
#define LDS_BYTES 119936

__device__ __forceinline__ float sigm(float x) { return 1.0f / (1.0f + __expf(-x)); }
__device__ __forceinline__ float tanh_fast(float x) { return 1.0f - 2.0f / (__expf(2.0f * x) + 1.0f); }

// Custom grid barrier: monotonic epoch, one atomic arrival per WG, agent-scope
// fences for h-buffer visibility (per-XCD L2 is not cross-coherent).
__device__ __forceinline__ void gbar(unsigned* cnt, unsigned* flag, unsigned epoch) {
    __syncthreads();   // all WG stores issued+waited (compiler emits vmcnt(0) before s_barrier)
    if (threadIdx.x == 0) {
        __builtin_amdgcn_fence(__ATOMIC_RELEASE, "agent");  // flush our XCD L2 to LLC
        unsigned old = __hip_atomic_fetch_add(cnt, 1u, __ATOMIC_RELAXED, __HIP_MEMORY_SCOPE_AGENT);
        if (old == epoch * 256u - 1u) {
            __hip_atomic_store(flag, epoch, __ATOMIC_RELEASE, __HIP_MEMORY_SCOPE_AGENT);
        } else {
            while (__hip_atomic_load(flag, __ATOMIC_RELAXED, __HIP_MEMORY_SCOPE_AGENT) < epoch)
                __builtin_amdgcn_s_sleep(1);
        }
        __builtin_amdgcn_fence(__ATOMIC_ACQUIRE, "agent");  // inv L1 + XCD L2 before next-phase loads
    }
    __syncthreads();
}

__global__ void __launch_bounds__(512)
lstm_persist(const float* __restrict__ x,
             const float* __restrict__ Wih0, const float* __restrict__ Whh0,
             const float* __restrict__ bih0, const float* __restrict__ bhh0,
             const float* __restrict__ Wih1, const float* __restrict__ Whh1,
             const float* __restrict__ bih1, const float* __restrict__ bhh1,
             const float* __restrict__ Wd, const float* __restrict__ bd,
             float* __restrict__ out, char* __restrict__ wsc)
{
    cg::grid_group grid = cg::this_grid();
    const int wg   = blockIdx.x;      // 0..255, owns h-cols [wg*4, wg*4+4)
    const int tid  = threadIdx.x;     // 0..511
    const int wave = tid >> 6;        // 0..7, owns batch rows [wave*16, wave*16+16)
    const int lane = tid & 63;
    const int l15  = lane & 15;
    const int quad = lane >> 4;

    _Float16* h0b = (_Float16*)(wsc + H0_OFF);   // [2][128][1024]
    _Float16* h1b = (_Float16*)(wsc + H1_OFF);   // [2][128][1024]
    _Float16* x16 = (_Float16*)(wsc + X16_OFF);  // [128][256][128]
    unsigned* bcnt = (unsigned*)(wsc + BAR_OFF);
    unsigned* bflag = bcnt + 16;                 // separate dwords, same region

    extern __shared__ char smem[];
    _Float16* w0l = (_Float16*)(smem);            // [16][1160]
    _Float16* w1l = (_Float16*)(smem + 37120);    // [16][2056]
    float*    gs0 = (float*)(smem + 102912);      // [16][132] col-major
    float*    gs1 = (float*)(smem + 111360);      // [16][132]
    float*    bs0 = (float*)(smem + 119808);      // [16]
    float*    bs1 = (float*)(smem + 119808 + 64); // [16]

    // ---------- init: stage this WG's weight slice into LDS (fp16) ----------
    for (int i = tid; i < 16 * 1152; i += 512) {
        int c = i / 1152, k = i - c * 1152;
        int gcol = ((c >> 2) << 10) + (wg << 2) + (c & 3);
        float v = (k < NIN) ? Wih0[gcol * NIN + k] : Whh0[gcol * NH + (k - NIN)];
        w0l[c * W0STRIDE + k] = (_Float16)v;
    }
    for (int i = tid; i < 16 * 2048; i += 512) {
        int c = i >> 11, k = i & 2047;
        int gcol = ((c >> 2) << 10) + (wg << 2) + (c & 3);
        float v = (k < NH) ? Wih1[gcol * NH + k] : Whh1[gcol * NH + (k - NH)];
        w1l[c * W1STRIDE + k] = (_Float16)v;
    }
    if (tid < 16) {
        int c = tid;
        int gcol = ((c >> 2) << 10) + (wg << 2) + (c & 3);
        bs0[c] = bih0[gcol] + bhh0[gcol];
        bs1[c] = bih1[gcol] + bhh1[gcol];
    }

    // ---------- init: zero h bufs, convert x to fp16, reset barrier state ----------
    {
        const int gtid = wg * 512 + tid;
        const int gsz  = 256 * 512;  // 131072
        float* hz = (float*)wsc;     // both h bufs = 1 MiB = 262144 floats
        for (int i = gtid; i < 262144; i += gsz) hz[i] = 0.0f;
        for (int i = gtid; i < NB * NT * NIN; i += gsz) x16[i] = (_Float16)x[i];
        if (gtid == 0) { *bcnt = 0u; *bflag = 0u; }   // d_ws is poisoned 0xAA each run
    }
    // one slow cg sync: publishes init data AND the zeroed barrier state
    __builtin_amdgcn_fence(__ATOMIC_RELEASE, "agent");
    grid.sync();
    __builtin_amdgcn_fence(__ATOMIC_ACQUIRE, "agent");

    float c0 = 0.0f, c1 = 0.0f;          // persistent cell state, 1 (b,hcol) pair/thread
    const int b_act = tid >> 2;          // batch row for activation stage
    const int jl    = tid & 3;           // local h-col
    const int hcol  = (wg << 2) + jl;

    // B-fragment row bases in LDS (n = l15), A k-offset quad*8 baked in
    const _Float16* w0row = w0l + l15 * W0STRIDE + quad * 8;
    const _Float16* w1row = w1l + l15 * W1STRIDE + quad * 8;

    // pipeline: phase p computes h0[p] (p<NT) and h1[p-1] (p>=1)
    for (int p = 0; p <= NT; ++p) {
        const _Float16* h0prev = h0b + ((p - 1) & 1) * (NB * NH);  // h0[p-1]
        const _Float16* h1pp   = h1b + (p & 1) * (NB * NH);        // h1[p-2]

        floatx4 acc0 = {0.f, 0.f, 0.f, 0.f};
        floatx4 acc1 = {0.f, 0.f, 0.f, 0.f};

        const _Float16* arow_h0 = h0prev + (size_t)(wave * 16 + l15) * NH + quad * 8;

        if (p < NT) {
            // x_t contribution to layer0 gates (K = 0..127)
            const _Float16* arow_x = x16 + (size_t)(wave * 16 + l15) * (NT * NIN) + p * NIN + quad * 8;
            #pragma unroll
            for (int kc = 0; kc < 4; ++kc) {
                half8 a = *(const half8*)(arow_x + kc * 32);
                half8 b = *(const half8*)(w0row + kc * 32);
                acc0 = __builtin_amdgcn_mfma_f32_16x16x32_f16(a, b, acc0, 0, 0, 0);
            }
        }

        // h0[p-1] contribution: feeds BOTH layer0 (W_hh0) and layer1 (W_ih1) — share A loads
        if (p >= 1 && p < NT) {
            const _Float16* b0 = w0row + NIN;
            #pragma unroll 8
            for (int kc = 0; kc < 32; ++kc) {
                half8 a  = *(const half8*)(arow_h0 + kc * 32);
                half8 v0 = *(const half8*)(b0 + kc * 32);
                half8 v1 = *(const half8*)(w1row + kc * 32);
                acc0 = __builtin_amdgcn_mfma_f32_16x16x32_f16(a, v0, acc0, 0, 0, 0);
                acc1 = __builtin_amdgcn_mfma_f32_16x16x32_f16(a, v1, acc1, 0, 0, 0);
            }
        } else if (p < NT) {  // p == 0
            const _Float16* b0 = w0row + NIN;
            #pragma unroll 8
            for (int kc = 0; kc < 32; ++kc) {
                half8 a  = *(const half8*)(arow_h0 + kc * 32);
                half8 v0 = *(const half8*)(b0 + kc * 32);
                acc0 = __builtin_amdgcn_mfma_f32_16x16x32_f16(a, v0, acc0, 0, 0, 0);
            }
        } else {              // p == NT
            #pragma unroll 8
            for (int kc = 0; kc < 32; ++kc) {
                half8 a  = *(const half8*)(arow_h0 + kc * 32);
                half8 v1 = *(const half8*)(w1row + kc * 32);
                acc1 = __builtin_amdgcn_mfma_f32_16x16x32_f16(a, v1, acc1, 0, 0, 0);
            }
        }

        if (p >= 1) {
            // h1[p-2] contribution to layer1 gates (K = 1024..2047)
            const _Float16* arow_h1 = h1pp + (size_t)(wave * 16 + l15) * NH + quad * 8;
            const _Float16* b1 = w1row + NH;
            #pragma unroll 8
            for (int kc = 0; kc < 32; ++kc) {
                half8 a = *(const half8*)(arow_h1 + kc * 32);
                half8 v = *(const half8*)(b1 + kc * 32);
                acc1 = __builtin_amdgcn_mfma_f32_16x16x32_f16(a, v, acc1, 0, 0, 0);
            }
        }

        // stash gate tiles to LDS, col-major: rows quad*4+r contiguous -> one b128
        if (p < NT) *(floatx4*)&gs0[l15 * GSTRIDE + wave * 16 + quad * 4] = acc0;
        if (p >= 1) *(floatx4*)&gs1[l15 * GSTRIDE + wave * 16 + quad * 4] = acc1;
        __syncthreads();

        // activation: 1 (b, hcol) pair per thread; gate cols c = gate*4 + jl
        if (p < NT) {
            float gi = gs0[(jl)      * GSTRIDE + b_act] + bs0[jl];
            float gf = gs0[(4 + jl)  * GSTRIDE + b_act] + bs0[4 + jl];
            float gg = gs0[(8 + jl)  * GSTRIDE + b_act] + bs0[8 + jl];
            float go = gs0[(12 + jl) * GSTRIDE + b_act] + bs0[12 + jl];
            c0 = sigm(gf) * c0 + sigm(gi) * tanh_fast(gg);
            float h = sigm(go) * tanh_fast(c0);
            h0b[(p & 1) * (NB * NH) + b_act * NH + hcol] = (_Float16)h;
        }
        if (p >= 1) {
            float gi = gs1[(jl)      * GSTRIDE + b_act] + bs1[jl];
            float gf = gs1[(4 + jl)  * GSTRIDE + b_act] + bs1[4 + jl];
            float gg = gs1[(8 + jl)  * GSTRIDE + b_act] + bs1[8 + jl];
            float go = gs1[(12 + jl) * GSTRIDE + b_act] + bs1[12 + jl];
            c1 = sigm(gf) * c1 + sigm(gi) * tanh_fast(gg);
            float h = sigm(go) * tanh_fast(c1);
            h1b[((p - 1) & 1) * (NB * NH) + b_act * NH + hcol] = (_Float16)h;
        }
        gbar(bcnt, bflag, (unsigned)(p + 1));
    }

    // dense head, parallel over batch: WG b computes out[b][0..1] from h1[255] (parity 1)
    if (wg < NB) {
        const _Float16* hrow = h1b + (NB * NH) + wg * NH;
        float hk0 = (float)hrow[tid * 2];
        float hk1 = (float)hrow[tid * 2 + 1];
        float p0 = hk0 * Wd[tid * 2] + hk1 * Wd[tid * 2 + 1];
        float p1 = hk0 * Wd[NH + tid * 2] + hk1 * Wd[NH + tid * 2 + 1];
        #pragma unroll
        for (int off = 32; off; off >>= 1) {
            p0 += __shfl_down(p0, off);
            p1 += __shfl_down(p1, off);
        }
        float* red = gs0;  // reuse LDS (all threads past gbar's trailing __syncthreads)
        if (lane == 0) { red[wave * 2] = p0; red[wave * 2 + 1] = p1; }
        __syncthreads();
        if (tid < 2) {
            float s = bd[tid];
            #pragma unroll
            for (int w = 0; w < 8; ++w) s += red[w * 2 + tid];
            out[wg * 2 + tid] = tanhf(s);
        }
    }
}

extern "C" void kernel_launch(void* const* d_in, const int* in_sizes, int n_in,
                              void* d_out, int out_size, void* d_ws, size_t ws_size,
                              hipStream_t stream) {
    const float* x    = (const float*)d_in[0];
    const float* Wih0 = (const float*)d_in[1];
    const float* Whh0 = (const float*)d_in[2];
    const float* bih0 = (const float*)d_in[3];
    const float* bhh0 = (const float*)d_in[4];
    const float* Wih1 = (const float*)d_in[5];
    const float* Whh1 = (const float*)d_in[6];
    const float* bih1 = (const float*)d_in[7];
    const float* bhh1 = (const float*)d_in[8];
    const float* Wd   = (const float*)d_in[9];
    const float* bd   = (const float*)d_in[10];
    float* out = (float*)d_out;
    char* ws = (char*)d_ws;

    hipFuncSetAttribute((const void*)lstm_persist,
                        hipFuncAttributeMaxDynamicSharedMemorySize, LDS_BYTES);

    void* kargs[] = { &x, &Wih0, &Whh0, &bih0, &bhh0, &Wih1, &Whh1, &bih1, &bhh1,
                      &Wd, &bd, &out, &ws };
    hipLaunchCooperativeKernel((void*)lstm_persist, dim3(256), dim3(512),
                               kargs, LDS_BYTES, stream);
}

// Round 4
// 6748.427 us; speedup vs baseline: 4.7560x; 1.2411x over previous
//
#include <hip/hip_runtime.h>
#include <hip/hip_fp16.h>
#include <hip/hip_cooperative_groups.h>

namespace cg = cooperative_groups;

typedef _Float16 half8 __attribute__((ext_vector_type(8)));
typedef float floatx4 __attribute__((ext_vector_type(4)));

#define NB 128
#define NT 256
#define NIN 128
#define NH 1024

// ws layout (bytes): h ping-pong buffers + fp16 x copy + barrier state
#define H0_OFF   0u          // 2 * 128*1024 half = 524288 B
#define H1_OFF   524288u     // 524288 B
#define X16_OFF  1048576u    // 128*256*128 half = 8388608 B
#define BAR_OFF  9437184u    // barrier region: 16 group lines @256B, root @4096, flag @4352

// LDS layout (bytes), carved from extern __shared__:
//  w0l: 16 cols x (1152+8) half = 37120
//  w1l: 16 cols x (2048+8) half = 65792   (base 37120)
//  gs0: 16 cols x 132 float     =  8448   (base 102912) col-major gate tile
//  gs1: 16 cols x 132 float     =  8448   (base 111360)
//  bs0/bs1: 16+16 float         =   128   (base 119808) -> total 119936
#define W0STRIDE 1160
#define W1STRIDE 2056
#define GSTRIDE  132
#define LDS_BYTES 119936

__device__ __forceinline__ float sigm(float x) { return 1.0f / (1.0f + __expf(-x)); }
__device__ __forceinline__ float tanh_fast(float x) { return 1.0f - 2.0f / (__expf(2.0f * x) + 1.0f); }

// Two-level grid barrier: 16 groups x 16 WGs. Group g = wg & 15 (same-XCD under
// round-robin dispatch). Separate cache lines for each group counter, root, flag.
// Caller must __syncthreads() before arrive (drains WG stores into L2).
__device__ __forceinline__ void gbar_arrive(char* bar, unsigned epoch, int wg) {
    __builtin_amdgcn_fence(__ATOMIC_RELEASE, "agent");  // flush XCD L2 to LLC
    unsigned* gcnt = (unsigned*)(bar + (wg & 15) * 256);
    unsigned old = __hip_atomic_fetch_add(gcnt, 1u, __ATOMIC_RELAXED, __HIP_MEMORY_SCOPE_AGENT);
    if (old == epoch * 16u - 1u) {        // last of my group
        unsigned* rcnt = (unsigned*)(bar + 4096);
        unsigned rold = __hip_atomic_fetch_add(rcnt, 1u, __ATOMIC_RELAXED, __HIP_MEMORY_SCOPE_AGENT);
        if (rold == epoch * 16u - 1u) {   // last group overall
            unsigned* flag = (unsigned*)(bar + 4352);
            __hip_atomic_store(flag, epoch, __ATOMIC_RELEASE, __HIP_MEMORY_SCOPE_AGENT);
        }
    }
}
__device__ __forceinline__ void gbar_wait(char* bar, unsigned epoch) {
    unsigned* flag = (unsigned*)(bar + 4352);
    while (__hip_atomic_load(flag, __ATOMIC_RELAXED, __HIP_MEMORY_SCOPE_AGENT) < epoch)
        __builtin_amdgcn_s_sleep(1);
    __builtin_amdgcn_fence(__ATOMIC_ACQUIRE, "agent");  // inv L1 + XCD L2
}

__global__ void __launch_bounds__(512)
lstm_persist(const float* __restrict__ x,
             const float* __restrict__ Wih0, const float* __restrict__ Whh0,
             const float* __restrict__ bih0, const float* __restrict__ bhh0,
             const float* __restrict__ Wih1, const float* __restrict__ Whh1,
             const float* __restrict__ bih1, const float* __restrict__ bhh1,
             const float* __restrict__ Wd, const float* __restrict__ bd,
             float* __restrict__ out, char* __restrict__ wsc)
{
    cg::grid_group grid = cg::this_grid();
    const int wg   = blockIdx.x;      // 0..255, owns h-cols [wg*4, wg*4+4)
    const int tid  = threadIdx.x;     // 0..511
    const int wave = tid >> 6;        // 0..7, owns batch rows [wave*16, wave*16+16)
    const int lane = tid & 63;
    const int l15  = lane & 15;
    const int quad = lane >> 4;

    _Float16* h0b = (_Float16*)(wsc + H0_OFF);   // [2][128][1024]
    _Float16* h1b = (_Float16*)(wsc + H1_OFF);   // [2][128][1024]
    _Float16* x16 = (_Float16*)(wsc + X16_OFF);  // [128][256][128]
    char* bar = wsc + BAR_OFF;

    extern __shared__ char smem[];
    _Float16* w0l = (_Float16*)(smem);            // [16][1160]
    _Float16* w1l = (_Float16*)(smem + 37120);    // [16][2056]
    float*    gs0 = (float*)(smem + 102912);      // [16][132] col-major
    float*    gs1 = (float*)(smem + 111360);      // [16][132]
    float*    bs0 = (float*)(smem + 119808);      // [16]
    float*    bs1 = (float*)(smem + 119808 + 64); // [16]

    // ---------- init: stage this WG's weight slice into LDS (fp16) ----------
    for (int i = tid; i < 16 * 1152; i += 512) {
        int c = i / 1152, k = i - c * 1152;
        int gcol = ((c >> 2) << 10) + (wg << 2) + (c & 3);
        float v = (k < NIN) ? Wih0[gcol * NIN + k] : Whh0[gcol * NH + (k - NIN)];
        w0l[c * W0STRIDE + k] = (_Float16)v;
    }
    for (int i = tid; i < 16 * 2048; i += 512) {
        int c = i >> 11, k = i & 2047;
        int gcol = ((c >> 2) << 10) + (wg << 2) + (c & 3);
        float v = (k < NH) ? Wih1[gcol * NH + k] : Whh1[gcol * NH + (k - NH)];
        w1l[c * W1STRIDE + k] = (_Float16)v;
    }
    if (tid < 16) {
        int c = tid;
        int gcol = ((c >> 2) << 10) + (wg << 2) + (c & 3);
        bs0[c] = bih0[gcol] + bhh0[gcol];
        bs1[c] = bih1[gcol] + bhh1[gcol];
    }

    // ---------- init: zero h bufs, convert x to fp16, reset barrier state ----------
    {
        const int gtid = wg * 512 + tid;
        const int gsz  = 256 * 512;  // 131072
        float* hz = (float*)wsc;     // both h bufs = 1 MiB = 262144 floats
        for (int i = gtid; i < 262144; i += gsz) hz[i] = 0.0f;
        for (int i = gtid; i < NB * NT * NIN; i += gsz) x16[i] = (_Float16)x[i];
        if (wg == 0 && tid < 18) {   // d_ws is poisoned 0xAA each run
            if (tid < 16)       *(unsigned*)(bar + tid * 256) = 0u;  // group counters
            else if (tid == 16) *(unsigned*)(bar + 4096) = 0u;       // root counter
            else                *(unsigned*)(bar + 4352) = 0u;       // flag
        }
    }
    // one slow cg sync: publishes init data AND the zeroed barrier state
    __builtin_amdgcn_fence(__ATOMIC_RELEASE, "agent");
    grid.sync();
    __builtin_amdgcn_fence(__ATOMIC_ACQUIRE, "agent");

    float c0 = 0.0f, c1 = 0.0f;          // persistent cell state, 1 (b,hcol) pair/thread
    const int b_act = tid >> 2;          // batch row for activation stage
    const int jl    = tid & 3;           // local h-col
    const int hcol  = (wg << 2) + jl;

    // B-fragment row bases in LDS (n = l15), A k-offset quad*8 baked in
    const _Float16* w0row = w0l + l15 * W0STRIDE + quad * 8;
    const _Float16* w1row = w1l + l15 * W1STRIDE + quad * 8;

    // x-part of layer0 gates for step p (h-independent): K = 0..127
    auto xpart = [&](int p) -> floatx4 {
        floatx4 acc = {0.f, 0.f, 0.f, 0.f};
        const _Float16* arow_x = x16 + (size_t)(wave * 16 + l15) * (NT * NIN) + p * NIN + quad * 8;
        #pragma unroll
        for (int kc = 0; kc < 4; ++kc) {
            half8 a = *(const half8*)(arow_x + kc * 32);
            half8 b = *(const half8*)(w0row + kc * 32);
            acc = __builtin_amdgcn_mfma_f32_16x16x32_f16(a, b, acc, 0, 0, 0);
        }
        return acc;
    };

    floatx4 accx = xpart(0);   // prologue for p=0

    // pipeline: phase p computes h0[p] (p<NT) and h1[p-1] (p>=1)
    for (int p = 0; p <= NT; ++p) {
        const _Float16* h0prev = h0b + ((p - 1) & 1) * (NB * NH);  // h0[p-1]
        const _Float16* h1pp   = h1b + (p & 1) * (NB * NH);        // h1[p-2]

        floatx4 acc0 = accx;   // x contribution precomputed during prior barrier window
        floatx4 acc1 = {0.f, 0.f, 0.f, 0.f};

        const _Float16* arow_h0 = h0prev + (size_t)(wave * 16 + l15) * NH + quad * 8;

        // h0[p-1] contribution: feeds BOTH layer0 (W_hh0) and layer1 (W_ih1) — share A loads
        if (p >= 1 && p < NT) {
            const _Float16* b0 = w0row + NIN;
            #pragma unroll 8
            for (int kc = 0; kc < 32; ++kc) {
                half8 a  = *(const half8*)(arow_h0 + kc * 32);
                half8 v0 = *(const half8*)(b0 + kc * 32);
                half8 v1 = *(const half8*)(w1row + kc * 32);
                acc0 = __builtin_amdgcn_mfma_f32_16x16x32_f16(a, v0, acc0, 0, 0, 0);
                acc1 = __builtin_amdgcn_mfma_f32_16x16x32_f16(a, v1, acc1, 0, 0, 0);
            }
        } else if (p < NT) {  // p == 0
            const _Float16* b0 = w0row + NIN;
            #pragma unroll 8
            for (int kc = 0; kc < 32; ++kc) {
                half8 a  = *(const half8*)(arow_h0 + kc * 32);
                half8 v0 = *(const half8*)(b0 + kc * 32);
                acc0 = __builtin_amdgcn_mfma_f32_16x16x32_f16(a, v0, acc0, 0, 0, 0);
            }
        } else {              // p == NT
            #pragma unroll 8
            for (int kc = 0; kc < 32; ++kc) {
                half8 a  = *(const half8*)(arow_h0 + kc * 32);
                half8 v1 = *(const half8*)(w1row + kc * 32);
                acc1 = __builtin_amdgcn_mfma_f32_16x16x32_f16(a, v1, acc1, 0, 0, 0);
            }
        }

        if (p >= 1) {
            // h1[p-2] contribution to layer1 gates (K = 1024..2047)
            const _Float16* arow_h1 = h1pp + (size_t)(wave * 16 + l15) * NH + quad * 8;
            const _Float16* b1 = w1row + NH;
            #pragma unroll 8
            for (int kc = 0; kc < 32; ++kc) {
                half8 a = *(const half8*)(arow_h1 + kc * 32);
                half8 v = *(const half8*)(b1 + kc * 32);
                acc1 = __builtin_amdgcn_mfma_f32_16x16x32_f16(a, v, acc1, 0, 0, 0);
            }
        }

        // stash gate tiles to LDS, col-major: rows quad*4+r contiguous -> one b128
        if (p < NT) *(floatx4*)&gs0[l15 * GSTRIDE + wave * 16 + quad * 4] = acc0;
        if (p >= 1) *(floatx4*)&gs1[l15 * GSTRIDE + wave * 16 + quad * 4] = acc1;
        __syncthreads();

        // activation: 1 (b, hcol) pair per thread; gate cols c = gate*4 + jl
        if (p < NT) {
            float gi = gs0[(jl)      * GSTRIDE + b_act] + bs0[jl];
            float gf = gs0[(4 + jl)  * GSTRIDE + b_act] + bs0[4 + jl];
            float gg = gs0[(8 + jl)  * GSTRIDE + b_act] + bs0[8 + jl];
            float go = gs0[(12 + jl) * GSTRIDE + b_act] + bs0[12 + jl];
            c0 = sigm(gf) * c0 + sigm(gi) * tanh_fast(gg);
            float h = sigm(go) * tanh_fast(c0);
            h0b[(p & 1) * (NB * NH) + b_act * NH + hcol] = (_Float16)h;
        }
        if (p >= 1) {
            float gi = gs1[(jl)      * GSTRIDE + b_act] + bs1[jl];
            float gf = gs1[(4 + jl)  * GSTRIDE + b_act] + bs1[4 + jl];
            float gg = gs1[(8 + jl)  * GSTRIDE + b_act] + bs1[8 + jl];
            float go = gs1[(12 + jl) * GSTRIDE + b_act] + bs1[12 + jl];
            c1 = sigm(gf) * c1 + sigm(gi) * tanh_fast(gg);
            float h = sigm(go) * tanh_fast(c1);
            h1b[((p - 1) & 1) * (NB * NH) + b_act * NH + hcol] = (_Float16)h;
        }

        // ---- barrier with overlap: arrive, compute next x-part during spin window ----
        __syncthreads();                       // all WG h-stores drained to L2
        if (tid == 0) gbar_arrive(bar, (unsigned)(p + 1), wg);
        if (p + 1 < NT) accx = xpart(p + 1);   // h-independent work hides spin latency
        if (tid == 0) gbar_wait(bar, (unsigned)(p + 1));
        __syncthreads();
    }

    // dense head, parallel over batch: WG b computes out[b][0..1] from h1[255] (parity 1)
    if (wg < NB) {
        const _Float16* hrow = h1b + (NB * NH) + wg * NH;
        float hk0 = (float)hrow[tid * 2];
        float hk1 = (float)hrow[tid * 2 + 1];
        float p0 = hk0 * Wd[tid * 2] + hk1 * Wd[tid * 2 + 1];
        float p1 = hk0 * Wd[NH + tid * 2] + hk1 * Wd[NH + tid * 2 + 1];
        #pragma unroll
        for (int off = 32; off; off >>= 1) {
            p0 += __shfl_down(p0, off);
            p1 += __shfl_down(p1, off);
        }
        float* red = gs0;  // reuse LDS (all threads past final __syncthreads)
        if (lane == 0) { red[wave * 2] = p0; red[wave * 2 + 1] = p1; }
        __syncthreads();
        if (tid < 2) {
            float s = bd[tid];
            #pragma unroll
            for (int w = 0; w < 8; ++w) s += red[w * 2 + tid];
            out[wg * 2 + tid] = tanhf(s);
        }
    }
}

extern "C" void kernel_launch(void* const* d_in, const int* in_sizes, int n_in,
                              void* d_out, int out_size, void* d_ws, size_t ws_size,
                              hipStream_t stream) {
    const float* x    = (const float*)d_in[0];
    const float* Wih0 = (const float*)d_in[1];
    const float* Whh0 = (const float*)d_in[2];
    const float* bih0 = (const float*)d_in[3];
    const float* bhh0 = (const float*)d_in[4];
    const float* Wih1 = (const float*)d_in[5];
    const float* Whh1 = (const float*)d_in[6];
    const float* bih1 = (const float*)d_in[7];
    const float* bhh1 = (const float*)d_in[8];
    const float* Wd   = (const float*)d_in[9];
    const float* bd   = (const float*)d_in[10];
    float* out = (float*)d_out;
    char* ws = (char*)d_ws;

    hipFuncSetAttribute((const void*)lstm_persist,
                        hipFuncAttributeMaxDynamicSharedMemorySize, LDS_BYTES);

    void* kargs[] = { &x, &Wih0, &Whh0, &bih0, &bhh0, &Wih1, &Whh1, &bih1, &bhh1,
                      &Wd, &bd, &out, &ws };
    hipLaunchCooperativeKernel((void*)lstm_persist, dim3(256), dim3(512),
                               kargs, LDS_BYTES, stream);
}